// Round 9
// baseline (433.432 us; speedup 1.0000x reference)
//
#include <hip/hip_runtime.h>
#include <stdint.h>
#include <stddef.h>

// ---------------------------------------------------------------------------
// BSplineKANLayer fused kernel — f32 I/O, fp16 MFMA internally.
//   out = tanh( [spline_basis(x) | silu(x)] @ [coeffs | base_weight]^T
//               + res_scale * x )
// GEMM: M=16384, N=512, K=4608.
//
// R9 (from R8 post-mortem: dur tracks FETCH/achieved-BW in every round;
// coeffs logical traffic = (M/BM)*8MB depends only on BM; XCD-pinning failed):
//  1. BM 128->256 (512 thr, 8 waves, grid (8,64) = 2 blocks/CU, 16 waves/CU
//     = same wave-TLP as R8): coeffs logical 1.02 GB -> 512 MB.
//  2. Phase-1 kernel converts coeffs/bwt to fp16 into d_ws, REORDERED into
//     per-round staging order: per round, waves 0-3 each read one contiguous
//     1 KB run (full-line granularity; 512 -> 256 MB; no per-round cvt VALU).
//     Cs (g0, 1/h) precomputed too. Host checks ws_size (needs ~4.7 MB);
//     template<bool WS> fallback reads f32 sources directly (R8-style).
//  3. All mechanics (swizzle: 0 conflicts measured; K-permutation; 2-barrier
//     round; basis8; epilogue C/D map) verbatim from the R5/R8-verified code.
// K-permutation (spline): round kt, chunk c holds dim = 128c + kt, halfword j
// = basis_j; B element = coeffs[n][1024c + 8kt + j]. Silu round u: chunk c
// holds dims 32u+8c..+7; B = bwt[n][32u+8c+j]. A and B agree -> GEMM exact.
// ---------------------------------------------------------------------------

typedef __attribute__((ext_vector_type(8))) _Float16 half8;  // 8 fp16 = 4 VGPRs
typedef __attribute__((ext_vector_type(4))) float f32x4;

#define IN_DIM   512
#define OUT_DIM  512

// RNE f32 -> fp16 pair packed in a uint (a low 16, b high 16)
__device__ __forceinline__ unsigned pk2(float a, float b) {
  _Float16 ha = (_Float16)a, hb = (_Float16)b;   // v_cvt_f16_f32 (RNE)
  unsigned short ua = __builtin_bit_cast(unsigned short, ha);
  unsigned short ub = __builtin_bit_cast(unsigned short, hb);
  return (unsigned)ua | ((unsigned)ub << 16);
}
__device__ __forceinline__ uint4 pk8(float4 a, float4 b) {
  uint4 r;
  r.x = pk2(a.x, a.y); r.y = pk2(a.z, a.w);
  r.z = pk2(b.x, b.y); r.w = pk2(b.z, b.w);
  return r;
}
// R5/R8-verified XOR-swizzle (measured ZERO bank conflicts).
__device__ __forceinline__ int swz(int r, int c) {
  return r * 4 + ((c + (r >> 1)) & 3);
}

// Windowed cubic basis (uniform grid; R5-verified numerics).
__device__ __forceinline__ uint4 basis8(float xv, float g0, float rh) {
  float u  = (xv - g0) * rh;
  float tf = floorf(u);
  float f  = u - tf;
  int   t  = (int)tf;
  bool valid = (u >= 0.f) && (u < 11.f);
  t = min(max(t, 0), 10);
  float f2 = f * f, f3 = f2 * f;
  float omf = 1.f - f;
  float v0 = omf * omf * omf;                                 // j = t-3
  float v1 = fmaf(f2, fmaf(3.f, f, -6.f), 4.f);               // j = t-2
  float v2 = fmaf(f, fmaf(f, fmaf(-3.f, f, 3.f), 3.f), 1.f);  // j = t-1
  float v3 = f3;                                              // j = t
  uint64_t pack = ((uint64_t)pk2(v2, v3) << 32) | (uint64_t)pk2(v0, v1);
  pack = valid ? pack : 0ull;
  const int base = 48 - 16 * t;        // halfword t-3 -> output bit 16*(t-3)
  uint4 r;
  uint32_t* rp = (uint32_t*)&r;
  #pragma unroll
  for (int i = 0; i < 4; ++i) {
    int amt = base + 32 * i;
    uint32_t lo = (amt >= 0 && amt < 64) ? (uint32_t)(pack >> amt) : 0u;
    uint32_t hi = (amt < 0 && amt > -64) ? (uint32_t)(pack << (-amt)) : 0u;
    rp[i] = lo | hi;
  }
  return r;
}

// ---------------------------------------------------------------------------
// Phase-1: fp16-convert + reorder coeffs/bwt into staging order; compute Cs.
//   wsC[(bc*128 + kt)*512 + n] = fp16x8 of coeffs[n][1024*bc + 8*kt .. +8]
//   wsB[(bc*16  + u )*512 + n] = fp16x8 of bwt[n][32*u + 8*bc .. +8]
// ---------------------------------------------------------------------------
__global__ void kan_prep(const float* __restrict__ coeffs,
                         const float* __restrict__ bwt,
                         const float* __restrict__ gsl,
                         const float* __restrict__ gstart,
                         uint4* __restrict__ wsC,    // 262144 uint4 = 4 MB
                         uint4* __restrict__ wsB,    // 32768 uint4 = 512 KB
                         float2* __restrict__ wsCs)  // 512 float2 = 4 KB
{
  int idx = blockIdx.x * 256 + threadIdx.x;
  if (idx < 512) {
    float v  = gsl[idx * 11];                            // uniform grid
    float sp = fmaxf(v, 0.f) + log1pf(expf(-fabsf(v)));  // softplus = step h
    wsCs[idx] = make_float2(gstart[idx], 1.f / sp);
  }
  if (idx < 262144) {
    int bc = idx >> 16, kt = (idx >> 9) & 127, n = idx & 511;
    const float* s = coeffs + (size_t)n * 4096 + bc * 1024 + kt * 8;
    wsC[idx] = pk8(*(const float4*)s, *(const float4*)(s + 4));
  } else if (idx < 294912) {
    int p = idx - 262144;
    int bc = p >> 13, u = (p >> 9) & 15, n = p & 511;
    const float* s = bwt + (size_t)n * 512 + u * 32 + bc * 8;
    wsB[p] = pk8(*(const float4*)s, *(const float4*)(s + 4));
  }
}

// ---------------------------------------------------------------------------
// Main: grid (8, 64), block 512 (8 waves). LDS: At 16K + Bt 4K + Cs 4K = 24 KB.
// Wave w: rows 64*(w&3).., cols 32*(w>>2)..; acc 4x2.
// ---------------------------------------------------------------------------
template <bool WS>
__global__ __launch_bounds__(512, 4) void kan_main(
    const float* __restrict__ x,       // (16384,512)
    const float* __restrict__ coeffs,  // (512,4096)  [fallback only]
    const float* __restrict__ bwt,     // (512,512)   [fallback only]
    const float* __restrict__ gsl,     // (512,11)    [fallback only]
    const float* __restrict__ gstart,  // (512,1)     [fallback only]
    const float* __restrict__ rsc,     // (1,)
    const uint4* __restrict__ wsC,
    const uint4* __restrict__ wsB,
    const float2* __restrict__ wsCs,
    float* __restrict__ out)           // (16384,512)
{
  __shared__ uint4 At[1024];       // [256 rows][4 chunks of 8 fp16], swizzled
  __shared__ uint4 Bt[256];        // [64 rows][4 chunks], swizzled
  __shared__ float2 Cs[512];       // per-dim (g0, 1/h)

  const int tid  = threadIdx.x;
  const int lane = tid & 63;
  const int wv   = tid >> 6;          // wave 0..7
  const int row0 = blockIdx.y << 8;   // 256-row batch block
  const int n0   = blockIdx.x << 6;   // 64-col block

  const int q    = lane >> 4;         // k-subchunk 0..3 (8 fp16 each)
  const int l15  = lane & 15;
  const int wrow = (wv & 3) << 6;     // 0/64/128/192
  const int wcol = (wv >> 2) << 5;    // 0/32

  if (WS) {
    Cs[tid & 511] = wsCs[tid & 511];
  } else {
    int d = tid;                       // 512 threads cover 512 dims
    float v  = gsl[d * 11];
    float sp = fmaxf(v, 0.f) + log1pf(expf(-fabsf(v)));
    Cs[d] = make_float2(gstart[d], 1.f / sp);
  }
  __syncthreads();

  f32x4 acc[4][2];
  #pragma unroll
  for (int a = 0; a < 4; ++a)
    #pragma unroll
    for (int b = 0; b < 2; ++b)
      acc[a][b] = (f32x4){0.f, 0.f, 0.f, 0.f};

  auto do_mfma = [&]() {
    half8 af[4], bg[2];
    #pragma unroll
    for (int tm = 0; tm < 4; ++tm) {
      int m = wrow + tm * 16 + l15;
      af[tm] = *(const half8*)&At[swz(m, q)];
    }
    #pragma unroll
    for (int tn = 0; tn < 2; ++tn) {
      int n = wcol + tn * 16 + l15;
      bg[tn] = *(const half8*)&Bt[swz(n, q)];
    }
    #pragma unroll
    for (int tm = 0; tm < 4; ++tm)
      #pragma unroll
      for (int tn = 0; tn < 2; ++tn)
        acc[tm][tn] = __builtin_amdgcn_mfma_f32_16x16x32_f16(
            af[tm], bg[tn], acc[tm][tn], 0, 0, 0);
  };

  // A-compute assignment: row = tid&255, chunks {cb, cb+1}, cb = 2*(tid>>8).
  const int arow = tid & 255;
  const int cb   = (tid >> 8) << 1;
  // B staging (tid<256 only; wave-uniform): wave w4 = tid>>6 reads chunk w4,
  // row = lane. WS path: contiguous 1 KB per wave per round.
  const int w4 = tid >> 6;                        // 0..3 when tid<256
  const uint4* bpC = wsC + ((size_t)w4 << 16) + n0 + lane;         // + 512*kt
  const float* bfC = coeffs + (size_t)(n0 + lane) * 4096 + (w4 << 10);  // +8*kt
  const uint4* bpB = wsB + ((size_t)w4 << 13) + n0 + lane;         // + 512*u
  const float* bfB = bwt + (size_t)(n0 + lane) * 512 + (w4 << 3);  // + 32*u

  // ====================== spline phase: 128 rounds ==========================
  const float* xpa = x + (size_t)(row0 + arow) * IN_DIM + (cb << 7);
  const float* xpb = xpa + 128;

  for (int kt4 = 0; kt4 < 32; ++kt4) {
    float4 xa = *(const float4*)(xpa + 4 * kt4);
    float4 xb = *(const float4*)(xpb + 4 * kt4);
    float xra[4] = {xa.x, xa.y, xa.z, xa.w};
    float xrb[4] = {xb.x, xb.y, xb.z, xb.w};
    #pragma unroll
    for (int j = 0; j < 4; ++j) {
      const int kt = kt4 * 4 + j;
      uint4 bw;
      if (tid < 256) {
        if (WS) {
          bw = bpC[kt << 9];                       // contiguous across lanes
        } else {
          const float* s = bfC + kt * 8;
          bw = pk8(*(const float4*)s, *(const float4*)(s + 4));
        }
      }
      float2 c0 = Cs[(cb << 7) + kt];              // wave-uniform
      float2 c1 = Cs[((cb + 1) << 7) + kt];
      uint4 p0 = basis8(xra[j], c0.x, c0.y);
      uint4 p1 = basis8(xrb[j], c1.x, c1.y);

      __syncthreads();                             // prev round fully read
      At[swz(arow, cb)]     = p0;
      At[swz(arow, cb + 1)] = p1;
      if (tid < 256) Bt[swz(lane, w4)] = bw;
      __syncthreads();                             // round published
      do_mfma();
    }
  }

  // ====================== silu phase: 16 rounds =============================
  const float* sx = x + (size_t)(row0 + arow) * IN_DIM;
  for (int u = 0; u < 16; ++u) {
    uint4 bw;
    if (tid < 256) {
      if (WS) {
        bw = bpB[u << 9];
      } else {
        const float* s = bfB + u * 32;
        bw = pk8(*(const float4*)s, *(const float4*)(s + 4));
      }
    }
    uint4 aw[2];
    #pragma unroll
    for (int cc = 0; cc < 2; ++cc) {
      const float* xs = sx + 32 * u + 8 * (cb + cc);
      float4 pa = *(const float4*)xs, pb = *(const float4*)(xs + 4);
      float f[8] = {pa.x, pa.y, pa.z, pa.w, pb.x, pb.y, pb.z, pb.w};
      #pragma unroll
      for (int jj = 0; jj < 8; ++jj) f[jj] = f[jj] / (1.f + __expf(-f[jj]));
      aw[cc].x = pk2(f[0], f[1]); aw[cc].y = pk2(f[2], f[3]);
      aw[cc].z = pk2(f[4], f[5]); aw[cc].w = pk2(f[6], f[7]);
    }
    __syncthreads();
    At[swz(arow, cb)]     = aw[0];
    At[swz(arow, cb + 1)] = aw[1];
    if (tid < 256) Bt[swz(lane, w4)] = bw;
    __syncthreads();
    do_mfma();
  }

  // ====================== epilogue: +res_scale*x, tanh, store ===============
  const float rs = rsc[0];
  #pragma unroll
  for (int tm = 0; tm < 4; ++tm) {
    #pragma unroll
    for (int tn = 0; tn < 2; ++tn) {
      #pragma unroll
      for (int r = 0; r < 4; ++r) {
        int m = row0 + wrow + tm * 16 + q * 4 + r;   // C/D: row=(lane>>4)*4+reg
        int n = n0 + wcol + tn * 16 + l15;           //      col=lane&15
        float xv = x[(size_t)m * IN_DIM + n];
        float y  = acc[tm][tn][r] + rs * xv;
        float e  = __expf(-2.f * fabsf(y));
        float t  = copysignf((1.f - e) / (1.f + e), y);
        out[(size_t)m * OUT_DIM + n] = t;
      }
    }
  }
}

// ---------------------------------------------------------------------------
extern "C" void kernel_launch(void* const* d_in, const int* in_sizes, int n_in,
                              void* d_out, int out_size, void* d_ws, size_t ws_size,
                              hipStream_t stream) {
  const float* x      = (const float*)d_in[0];
  const float* coeffs = (const float*)d_in[1];
  const float* bwt    = (const float*)d_in[2];
  const float* gsl    = (const float*)d_in[3];
  const float* gstart = (const float*)d_in[4];
  const float* rsc    = (const float*)d_in[5];
  float* out = (float*)d_out;
  (void)in_sizes; (void)n_in; (void)out_size;

  const size_t needC = 262144, needB = 32768;            // uint4 counts
  const size_t need_bytes = (needC + needB) * 16 + 512 * 8;  // ~4.72 MB
  uint4*  wsC  = (uint4*)d_ws;
  uint4*  wsB  = wsC + needC;
  float2* wsCs = (float2*)(wsB + needB);

  if (d_ws && ws_size >= need_bytes) {
    hipLaunchKernelGGL(kan_prep, dim3(1152), dim3(256), 0, stream,
                       coeffs, bwt, gsl, gstart, wsC, wsB, wsCs);
    hipLaunchKernelGGL((kan_main<true>), dim3(8, 64), dim3(512), 0, stream,
                       x, coeffs, bwt, gsl, gstart, rsc, wsC, wsB, wsCs, out);
  } else {
    hipLaunchKernelGGL((kan_main<false>), dim3(8, 64), dim3(512), 0, stream,
                       x, coeffs, bwt, gsl, gstart, rsc,
                       (const uint4*)nullptr, (const uint4*)nullptr,
                       (const float2*)nullptr, out);
  }
}